// Round 1
// baseline (1420.393 us; speedup 1.0000x reference)
//
#include <hip/hip_runtime.h>
#include <math.h>

// Problem constants (HiRNNDecoder)
constexpr int cB = 64, cS = 400, cH = 1024, cM = 1024, cE = 512, cV = 32000, cA = 8;
constexpr int cHM = cH + cM;   // 2048
constexpr int cG3 = 3 * cH;    // 3072
constexpr int PEOS_TOK = 4;
constexpr int MAXSG = 12;      // max subgroups of <=16 samples (worst case 11)

// ---- workspace layout (float offsets) ----
constexpr size_t WS_GI_G  = 0;
constexpr size_t WS_GH_G  = WS_GI_G + (size_t)cB * cG3;
constexpr size_t WS_GI_D  = WS_GH_G + (size_t)cB * cG3;
constexpr size_t WS_GH_D  = WS_GI_D + (size_t)cB * cG3;
constexpr size_t WS_HEFF  = WS_GH_D + (size_t)cB * cG3;
constexpr size_t WS_HNEXT = WS_HEFF + (size_t)cB * cH;
constexpr size_t WS_PROJ  = WS_HNEXT + (size_t)cB * cH;
constexpr size_t WS_XCAT  = WS_PROJ + (size_t)cB * cM;
constexpr size_t WS_H1    = WS_XCAT + (size_t)cB * cHM;
constexpr size_t WS_PGEN  = WS_H1 + (size_t)cB * cH;
constexpr size_t WS_SG    = WS_PGEN + cB;  // int region

// ---- output layout (float offsets, reference return order) ----
constexpr size_t O_VOCAB = 0;
constexpr size_t O_FINAL = O_VOCAB + (size_t)cB * cV;
constexpr size_t O_HNEXT = O_FINAL + (size_t)cB * cV;
constexpr size_t O_CTX   = O_HNEXT + (size_t)cB * cH;
constexpr size_t O_ATTN  = O_CTX + (size_t)cB * cM;
constexpr size_t O_PGEN  = O_ATTN + (size_t)cB * cS;
constexpr size_t O_COV   = O_PGEN + cB;
constexpr size_t O_SENT  = O_COV + (size_t)cB * cS;
constexpr size_t O_WAH   = O_SENT + cB;

__device__ __forceinline__ float sigmf(float x) { return 1.f / (1.f + __expf(-x)); }

// ------------------------------------------------------------------
// K0: bucket samples by aspect into subgroups of <=16
// ------------------------------------------------------------------
__global__ void group_kernel(const int* __restrict__ aspect_id,
                             int* __restrict__ sgcount, int* __restrict__ sgaspect,
                             int* __restrict__ sgsamp) {
  if (threadIdx.x != 0 || blockIdx.x != 0) return;
  int cnt[cA];
  int lists[cA][cB];
  for (int a = 0; a < cA; a++) cnt[a] = 0;
  for (int b = 0; b < cB; b++) { int a = aspect_id[b]; lists[a][cnt[a]++] = b; }
  int g = 0;
  for (int a = 0; a < cA; a++) {
    for (int off = 0; off < cnt[a]; off += 16) {
      int c = cnt[a] - off; if (c > 16) c = 16;
      sgcount[g] = c; sgaspect[g] = a;
      for (int i = 0; i < 16; i++) sgsamp[g * 16 + i] = lists[a][off + (i < c ? i : 0)];
      g++;
    }
  }
  for (; g < MAXSG; g++) sgcount[g] = 0;
}

// ------------------------------------------------------------------
// Generic skinny GEMM: C[64][N] = X[64][K] @ W[N][K]^T (+bias)
// lane = sample (64 lanes), 8 cols/wave, X staged in LDS, W streamed
// (uniform address per wave -> 1 txn/load). MASKED: W/bias indexed by
// blockIdx.y aspect, rows written only for matching samples.
// ------------------------------------------------------------------
template <int K, bool HAS_IDX, bool MASKED>
__global__ __launch_bounds__(256) void gemm_xw(
    const float* __restrict__ X, const int* __restrict__ xidx,
    const float* __restrict__ W, const float* __restrict__ bias,
    float* __restrict__ Cout, const int N, const int* __restrict__ aspect_id) {
  constexpr int TK = 128;
  __shared__ float Xs[64][TK + 4];  // +4 keeps 16B alignment, spreads banks
  const int t = threadIdx.x, lane = t & 63, wave = t >> 6;
  const int a = MASKED ? blockIdx.y : 0;
  const float* Wa = W + (size_t)a * (size_t)N * K;
  const int n0 = blockIdx.x * 32 + wave * 8;
  float acc[8] = {};
  for (int kt = 0; kt < K; kt += TK) {
    for (int i = t; i < 64 * TK; i += 256) {
      const int r = i / TK, c = i % TK;
      const float* xr = HAS_IDX ? (X + (size_t)xidx[r] * K) : (X + (size_t)r * K);
      Xs[r][c] = xr[kt + c];
    }
    __syncthreads();
#pragma unroll 4
    for (int k = 0; k < TK; k += 4) {
      const float4 xv = *(const float4*)&Xs[lane][k];
#pragma unroll
      for (int j = 0; j < 8; j++) {
        const float4 wv = *(const float4*)(Wa + (size_t)(n0 + j) * K + (kt + k));
        acc[j] += xv.x * wv.x + xv.y * wv.y + xv.z * wv.z + xv.w * wv.w;
      }
    }
    __syncthreads();
  }
  if (MASKED && aspect_id[lane] != a) return;
  const float* bb = bias ? (MASKED ? bias + (size_t)a * N : bias) : nullptr;
#pragma unroll
  for (int j = 0; j < 8; j++) {
    float v = acc[j];
    if (bb) v += bb[n0 + j];
    Cout[(size_t)lane * N + (n0 + j)] = v;
  }
}

// ------------------------------------------------------------------
// GRU gate kernels (torch GRUCell math, gates r,z,n)
// ------------------------------------------------------------------
__global__ __launch_bounds__(256) void gate1_kernel(
    const float* __restrict__ gi, const float* __restrict__ gh,
    const float* __restrict__ bih, const float* __restrict__ bhh,
    const float* __restrict__ h_in, const float* __restrict__ hh,
    const int* __restrict__ y, const float* __restrict__ ssin,
    float* __restrict__ h_eff, float* __restrict__ d_sent) {
  const int idx = blockIdx.x * 256 + threadIdx.x;
  const int b = idx >> 10, j = idx & 1023;
  const float ir  = gi[(size_t)b * cG3 + j]          + bih[j];
  const float iz  = gi[(size_t)b * cG3 + cH + j]     + bih[cH + j];
  const float in_ = gi[(size_t)b * cG3 + 2 * cH + j] + bih[2 * cH + j];
  const float hr  = gh[(size_t)b * cG3 + j]          + bhh[j];
  const float hz  = gh[(size_t)b * cG3 + cH + j]     + bhh[cH + j];
  const float hn  = gh[(size_t)b * cG3 + 2 * cH + j] + bhh[2 * cH + j];
  const float r = sigmf(ir + hr), z = sigmf(iz + hz);
  const float n = tanhf(in_ + r * hn);
  const float hnew = (1.f - z) * n + z * hh[(size_t)b * cH + j];
  const bool peos = (y[b] == PEOS_TOK);
  h_eff[(size_t)b * cH + j] = peos ? hnew : h_in[(size_t)b * cH + j];
  if (j == 0) d_sent[b] = peos ? 1.f : ssin[b];
}

__global__ __launch_bounds__(256) void gate2_kernel(
    const float* __restrict__ gi, const float* __restrict__ gh,
    const float* __restrict__ bih, const float* __restrict__ bhh,
    const float* __restrict__ hh, float* __restrict__ h_ws,
    float* __restrict__ h_out) {
  const int idx = blockIdx.x * 256 + threadIdx.x;
  const int b = idx >> 10, j = idx & 1023;
  const float ir  = gi[(size_t)b * cG3 + j]          + bih[j];
  const float iz  = gi[(size_t)b * cG3 + cH + j]     + bih[cH + j];
  const float in_ = gi[(size_t)b * cG3 + 2 * cH + j] + bih[2 * cH + j];
  const float hr  = gh[(size_t)b * cG3 + j]          + bhh[j];
  const float hz  = gh[(size_t)b * cG3 + cH + j]     + bhh[cH + j];
  const float hn  = gh[(size_t)b * cG3 + 2 * cH + j] + bhh[2 * cH + j];
  const float r = sigmf(ir + hr), z = sigmf(iz + hz);
  const float n = tanhf(in_ + r * hn);
  const float hnew = (1.f - z) * n + z * hh[(size_t)b * cH + j];
  h_ws[(size_t)b * cH + j] = hnew;
  h_out[(size_t)b * cH + j] = hnew;
}

// ------------------------------------------------------------------
// Attention: per-sample block. scores -> masked softmax -> context.
// Also assembles xcat = [context, h_next] for W1/pgen.
// ------------------------------------------------------------------
__global__ __launch_bounds__(256) void attn_kernel(
    const float* __restrict__ mb, const float* __restrict__ proj,
    const float* __restrict__ mask, const float* __restrict__ h_next,
    float* __restrict__ d_attn, float* __restrict__ d_ctx,
    float* __restrict__ xcat) {
  const int b = blockIdx.x, t = threadIdx.x, lane = t & 63, wave = t >> 6;
  __shared__ float sc[cS];
  __shared__ float red[4];
  const float* mbb = mb + (size_t)b * cS * cM;
  float4 p4[4];
#pragma unroll
  for (int j = 0; j < 4; j++)
    p4[j] = *(const float4*)(proj + (size_t)b * cM + j * 256 + lane * 4);
  for (int s = wave; s < cS; s += 4) {
    const float* row = mbb + (size_t)s * cM;
    float acc = 0.f;
#pragma unroll
    for (int j = 0; j < 4; j++) {
      const float4 v = *(const float4*)(row + j * 256 + lane * 4);
      acc += v.x * p4[j].x + v.y * p4[j].y + v.z * p4[j].z + v.w * p4[j].w;
    }
#pragma unroll
    for (int o = 32; o > 0; o >>= 1) acc += __shfl_xor(acc, o);
    if (lane == 0) sc[s] = (mask[(size_t)b * cS + s] > 0.f) ? acc : -1e9f;
  }
  __syncthreads();
  float lm = -1e30f;
  for (int i = t; i < cS; i += 256) lm = fmaxf(lm, sc[i]);
#pragma unroll
  for (int o = 32; o > 0; o >>= 1) lm = fmaxf(lm, __shfl_xor(lm, o));
  if (lane == 0) red[wave] = lm;
  __syncthreads();
  const float Mx = fmaxf(fmaxf(red[0], red[1]), fmaxf(red[2], red[3]));
  __syncthreads();
  float ls = 0.f;
  for (int i = t; i < cS; i += 256) { float e = __expf(sc[i] - Mx); sc[i] = e; ls += e; }
#pragma unroll
  for (int o = 32; o > 0; o >>= 1) ls += __shfl_xor(ls, o);
  if (lane == 0) red[wave] = ls;
  __syncthreads();
  const float inv = 1.f / (red[0] + red[1] + red[2] + red[3]);
  for (int i = t; i < cS; i += 256) {
    const float v = sc[i] * inv;
    sc[i] = v;
    d_attn[(size_t)b * cS + i] = v;
  }
  __syncthreads();
  float4 c = {0.f, 0.f, 0.f, 0.f};
  for (int s = 0; s < cS; s++) {
    const float av = sc[s];
    const float4 v = *(const float4*)(mbb + (size_t)s * cM + t * 4);
    c.x += av * v.x; c.y += av * v.y; c.z += av * v.z; c.w += av * v.w;
  }
  *(float4*)(d_ctx + (size_t)b * cM + t * 4) = c;
  *(float4*)(xcat + (size_t)b * cHM + t * 4) = c;
  *(float4*)(xcat + (size_t)b * cHM + cM + t * 4) =
      *(const float4*)(h_next + (size_t)b * cH + t * 4);
}

// ------------------------------------------------------------------
// p_gen = sigmoid(pgen_W . [context, h_next, y_emb] + pgen_b)
// ------------------------------------------------------------------
__global__ __launch_bounds__(64) void pgen_kernel(
    const float* __restrict__ xcat, const float* __restrict__ embedding,
    const int* __restrict__ y, const float* __restrict__ pW,
    const float* __restrict__ pb, float* __restrict__ d_pgen,
    float* __restrict__ ws_pgen) {
  const int b = blockIdx.x, l = threadIdx.x;
  float acc = 0.f;
  for (int k = l; k < cHM; k += 64) acc += xcat[(size_t)b * cHM + k] * pW[k];
  const float* er = embedding + (size_t)y[b] * cE;
  for (int k = l; k < cE; k += 64) acc += er[k] * pW[cHM + k];
#pragma unroll
  for (int o = 32; o > 0; o >>= 1) acc += __shfl_xor(acc, o);
  if (l == 0) {
    const float pg = sigmf(acc + pb[0]);
    d_pgen[b] = pg;
    ws_pgen[b] = pg;
  }
}

// ------------------------------------------------------------------
// Logits: subgroup (<=16 samples, one aspect) x 1024 vocab cols/block.
// h1 rows in LDS (64KB), W2 rows streamed f4/lane. 4 cols/thread.
// ------------------------------------------------------------------
__global__ __launch_bounds__(256) void logits_kernel(
    const float* __restrict__ h1, const float* __restrict__ W2,
    const float* __restrict__ b2, const int* __restrict__ sgcount,
    const int* __restrict__ sgaspect, const int* __restrict__ sgsamp,
    float* __restrict__ logits) {
  const int g = blockIdx.y;
  const int ns = sgcount[g];
  if (ns == 0) return;
  const int a = sgaspect[g];
  __shared__ float Xs[16][cH];  // 64 KB
  const int t = threadIdx.x;
  for (int i = t; i < 16 * cH; i += 256) {
    const int s = i >> 10, k = i & (cH - 1);
    Xs[s][k] = h1[(size_t)sgsamp[g * 16 + s] * cH + k];
  }
  __syncthreads();
  const float* Wa = W2 + (size_t)a * cV * cH;
  const int n0 = blockIdx.x * 1024;
  const float* wp[4];
  bool val[4];
#pragma unroll
  for (int j = 0; j < 4; j++) {
    const int n = n0 + j * 256 + t;
    val[j] = (n < cV);
    wp[j] = Wa + (size_t)(val[j] ? n : 0) * cH;
  }
  float acc[4][16] = {};
#pragma unroll 2
  for (int k = 0; k < cH; k += 4) {
    float4 w[4];
#pragma unroll
    for (int j = 0; j < 4; j++) w[j] = *(const float4*)(wp[j] + k);
#pragma unroll
    for (int s = 0; s < 16; s++) {
      const float4 x = *(const float4*)&Xs[s][k];
#pragma unroll
      for (int j = 0; j < 4; j++)
        acc[j][s] += w[j].x * x.x + w[j].y * x.y + w[j].z * x.z + w[j].w * x.w;
    }
  }
#pragma unroll
  for (int s = 0; s < 16; s++) {
    if (s < ns) {
      const size_t bs = (size_t)sgsamp[g * 16 + s];
#pragma unroll
      for (int j = 0; j < 4; j++)
        if (val[j]) {
          const int n = n0 + j * 256 + t;
          logits[bs * cV + n] = acc[j][s] + b2[(size_t)a * cV + n];
        }
    }
  }
}

// ------------------------------------------------------------------
// Finalize: softmax over V (in-place: logits region becomes vocab_dist),
// final = pgen*vocab, then pointer scatter-add.
// ------------------------------------------------------------------
__global__ __launch_bounds__(256) void finalize_kernel(
    float* __restrict__ vocab, float* __restrict__ final_dist,
    const float* __restrict__ pgen, const float* __restrict__ attn,
    const int* __restrict__ src) {
  __shared__ float red[256];
  const int b = blockIdx.x, t = threadIdx.x;
  float* lb = vocab + (size_t)b * cV;
  float* fb = final_dist + (size_t)b * cV;
  float m = -1e30f;
  for (int v = t; v < cV; v += 256) m = fmaxf(m, lb[v]);
  red[t] = m; __syncthreads();
  for (int o = 128; o > 0; o >>= 1) {
    if (t < o) red[t] = fmaxf(red[t], red[t + o]);
    __syncthreads();
  }
  m = red[0]; __syncthreads();
  float l = 0.f;
  for (int v = t; v < cV; v += 256) l += __expf(lb[v] - m);
  red[t] = l; __syncthreads();
  for (int o = 128; o > 0; o >>= 1) {
    if (t < o) red[t] += red[t + o];
    __syncthreads();
  }
  l = red[0];
  const float inv = 1.f / l;
  const float pg = pgen[b];
  for (int v = t; v < cV; v += 256) {
    const float e = __expf(lb[v] - m) * inv;
    lb[v] = e;
    fb[v] = pg * e;
  }
  __syncthreads();
  const float cp = 1.f - pg;
  for (int s = t; s < cS; s += 256)
    atomicAdd(fb + src[(size_t)b * cS + s], cp * attn[(size_t)b * cS + s]);
}

// ------------------------------------------------------------------
extern "C" void kernel_launch(void* const* d_in, const int* in_sizes, int n_in,
                              void* d_out, int out_size, void* d_ws, size_t ws_size,
                              hipStream_t stream) {
  const int*   y      = (const int*)d_in[0];
  const float* h      = (const float*)d_in[1];
  const float* mb     = (const float*)d_in[2];
  const float* mask   = (const float*)d_in[3];
  const int*   src    = (const int*)d_in[4];
  const int*   aspect = (const int*)d_in[5];
  // d_in[6] asp_hidden: unused by reference
  const float* htinit = (const float*)d_in[7];
  const float* ssin   = (const float*)d_in[8];
  const float* cov    = (const float*)d_in[9];
  const float* wah    = (const float*)d_in[10];
  const float* emb    = (const float*)d_in[11];
  const float* gWih   = (const float*)d_in[12];
  const float* gWhh   = (const float*)d_in[13];
  const float* gbih   = (const float*)d_in[14];
  const float* gbhh   = (const float*)d_in[15];
  const float* ggWih  = (const float*)d_in[16];
  const float* ggWhh  = (const float*)d_in[17];
  const float* ggbih  = (const float*)d_in[18];
  const float* ggbhh  = (const float*)d_in[19];
  const float* attnW  = (const float*)d_in[20];
  const float* attnb  = (const float*)d_in[21];
  const float* pW     = (const float*)d_in[22];
  const float* pb     = (const float*)d_in[23];
  const float* W1     = (const float*)d_in[24];
  const float* b1     = (const float*)d_in[25];
  const float* W2     = (const float*)d_in[26];
  const float* b2     = (const float*)d_in[27];

  float* out = (float*)d_out;
  float* ws  = (float*)d_ws;
  int* sg       = (int*)(ws + WS_SG);
  int* sgcount  = sg;
  int* sgaspect = sg + MAXSG;
  int* sgsamp   = sg + 2 * MAXSG;

  // 0) aspect subgrouping
  group_kernel<<<1, 64, 0, stream>>>(aspect, sgcount, sgaspect, sgsamp);
  // 1) hierarchical GRU (g_*): gi = h @ g_W_ih^T ; gh = h_t_init @ g_W_hh^T
  gemm_xw<1024, false, false><<<dim3(cG3 / 32), 256, 0, stream>>>(
      h, nullptr, ggWih, nullptr, ws + WS_GI_G, cG3, nullptr);
  gemm_xw<1024, false, false><<<dim3(cG3 / 32), 256, 0, stream>>>(
      htinit, nullptr, ggWhh, nullptr, ws + WS_GH_G, cG3, nullptr);
  gate1_kernel<<<cB * cH / 256, 256, 0, stream>>>(
      ws + WS_GI_G, ws + WS_GH_G, ggbih, ggbhh, h, htinit, y, ssin,
      ws + WS_HEFF, out + O_SENT);
  // 2) decoder GRU: gi = emb[y] @ gru_W_ih^T ; gh = h_eff @ gru_W_hh^T
  gemm_xw<512, true, false><<<dim3(cG3 / 32), 256, 0, stream>>>(
      emb, y, gWih, nullptr, ws + WS_GI_D, cG3, nullptr);
  gemm_xw<1024, false, false><<<dim3(cG3 / 32), 256, 0, stream>>>(
      ws + WS_HEFF, nullptr, gWhh, nullptr, ws + WS_GH_D, cG3, nullptr);
  gate2_kernel<<<cB * cH / 256, 256, 0, stream>>>(
      ws + WS_GI_D, ws + WS_GH_D, gbih, gbhh, ws + WS_HEFF,
      ws + WS_HNEXT, out + O_HNEXT);
  // 3) attention
  gemm_xw<1024, false, false><<<dim3(cM / 32), 256, 0, stream>>>(
      ws + WS_HNEXT, nullptr, attnW, attnb, ws + WS_PROJ, cM, nullptr);
  attn_kernel<<<cB, 256, 0, stream>>>(mb, ws + WS_PROJ, mask, ws + WS_HNEXT,
                                      out + O_ATTN, out + O_CTX, ws + WS_XCAT);
  pgen_kernel<<<cB, 64, 0, stream>>>(ws + WS_XCAT, emb, y, pW, pb,
                                     out + O_PGEN, ws + WS_PGEN);
  // 4) aspect head
  gemm_xw<2048, false, true><<<dim3(cH / 32, cA), 256, 0, stream>>>(
      ws + WS_XCAT, nullptr, W1, b1, ws + WS_H1, cH, aspect);
  logits_kernel<<<dim3(32, MAXSG), 256, 0, stream>>>(
      ws + WS_H1, W2, b2, sgcount, sgaspect, sgsamp, out + O_VOCAB);
  // 5) softmax + copy gate + pointer scatter
  finalize_kernel<<<cB, 256, 0, stream>>>(out + O_VOCAB, out + O_FINAL,
                                          ws + WS_PGEN, out + O_ATTN, src);
  // 6) passthrough outputs
  hipMemcpyAsync(out + O_COV, cov, (size_t)cB * cS * sizeof(float),
                 hipMemcpyDeviceToDevice, stream);
  hipMemcpyAsync(out + O_WAH, wah, (size_t)cB * cM * sizeof(float),
                 hipMemcpyDeviceToDevice, stream);
}

// Round 3
// 958.166 us; speedup vs baseline: 1.4824x; 1.4824x over previous
//
#include <hip/hip_runtime.h>
#include <math.h>

// Problem constants (HiRNNDecoder)
constexpr int cB = 64, cS = 400, cH = 1024, cM = 1024, cE = 512, cV = 32000, cA = 8;
constexpr int cHM = cH + cM;   // 2048
constexpr int cG3 = 3 * cH;    // 3072
constexpr int PEOS_TOK = 4;
constexpr int MAXSG = 12;

// ---- workspace layout (float offsets) ----
constexpr size_t WS_P0    = 0;                               // gi_g parts [4][64][3072]
constexpr size_t WS_P1    = WS_P0 + (size_t)4 * cB * cG3;    // gh_g parts [4][64][3072]
constexpr size_t WS_P2    = WS_P1 + (size_t)4 * cB * cG3;    // gi_d parts [2][64][3072]
constexpr size_t WS_P3    = WS_P2 + (size_t)2 * cB * cG3;    // gh_d parts [4][64][3072]
constexpr size_t WS_P4    = WS_P3 + (size_t)4 * cB * cG3;    // proj parts [4][64][1024]
constexpr size_t WS_P5    = WS_P4 + (size_t)4 * cB * cM;     // h1 parts [2][64][1024]
constexpr size_t WS_HEFF  = WS_P5 + (size_t)2 * cB * cH;
constexpr size_t WS_HNEXT = WS_HEFF + (size_t)cB * cH;
constexpr size_t WS_XCAT  = WS_HNEXT + (size_t)cB * cH;
constexpr size_t WS_SCORE = WS_XCAT + (size_t)cB * cHM;
constexpr size_t WS_PGEN  = WS_SCORE + (size_t)cB * cS;
constexpr size_t WS_MPART = WS_PGEN + cB;
constexpr size_t WS_LPART = WS_MPART + (size_t)cB * 4;
constexpr size_t WS_SG    = WS_LPART + (size_t)cB * 4;       // int region

// ---- output layout (float offsets, reference return order) ----
constexpr size_t O_VOCAB = 0;
constexpr size_t O_FINAL = O_VOCAB + (size_t)cB * cV;
constexpr size_t O_HNEXT = O_FINAL + (size_t)cB * cV;
constexpr size_t O_CTX   = O_HNEXT + (size_t)cB * cH;
constexpr size_t O_ATTN  = O_CTX + (size_t)cB * cM;
constexpr size_t O_PGEN  = O_ATTN + (size_t)cB * cS;
constexpr size_t O_COV   = O_PGEN + cB;
constexpr size_t O_SENT  = O_COV + (size_t)cB * cS;
constexpr size_t O_WAH   = O_SENT + cB;

__device__ __forceinline__ float sigmf(float x) { return 1.f / (1.f + __expf(-x)); }

// ------------------------------------------------------------------
// K0: bucket samples by aspect into subgroups of <=16
// ------------------------------------------------------------------
__global__ void group_kernel(const int* __restrict__ aspect_id,
                             int* __restrict__ sgcount, int* __restrict__ sgaspect,
                             int* __restrict__ sgsamp) {
  if (threadIdx.x != 0 || blockIdx.x != 0) return;
  int cnt[cA];
  int lists[cA][cB];
  for (int a = 0; a < cA; a++) cnt[a] = 0;
  for (int b = 0; b < cB; b++) { int a = aspect_id[b]; lists[a][cnt[a]++] = b; }
  int g = 0;
  for (int a = 0; a < cA; a++) {
    for (int off = 0; off < cnt[a]; off += 16) {
      int c = cnt[a] - off; if (c > 16) c = 16;
      sgcount[g] = c; sgaspect[g] = a;
      for (int i = 0; i < 16; i++) sgsamp[g * 16 + i] = lists[a][off + (i < c ? i : 0)];
      g++;
    }
  }
  for (; g < MAXSG; g++) sgcount[g] = 0;
}

// ==================================================================
// Split-K skinny GEMM core: 64 samples (lane), 32 cols/block (8/wave),
// one 256-wide K chunk per blockIdx.y. X tile XOR-swizzled in LDS so
// the per-lane ds_read_b128 is conflict-free; W row pointers hoisted
// via readfirstlane (wave-uniform -> scalar-load candidates).
// ==================================================================

// Merged input GEMMs: z=0 gi_g (h @ gWih_g^T), z=1 gh_g (htinit @ gWhh_g^T),
// z=2 gi_d (emb[y] @ gWih_d^T, K=512, 2 splits). grid (96, 4, 3).
__global__ __launch_bounds__(256) void gemm3_kernel(
    const float* __restrict__ h, const float* __restrict__ htinit,
    const float* __restrict__ emb, const int* __restrict__ y,
    const float* __restrict__ Wg_ih, const float* __restrict__ Wg_hh,
    const float* __restrict__ Wd_ih,
    float* __restrict__ P0, float* __restrict__ P1, float* __restrict__ P2) {
  const int z = blockIdx.z, split = blockIdx.y;
  if (z == 2 && split >= 2) return;
  const int t = threadIdx.x, lane = t & 63, wave = t >> 6;
  const int n0 = blockIdx.x * 32 + wave * 8;
  const int K = (z == 2) ? cE : cH;
  const float* W = (z == 0) ? Wg_ih : (z == 1) ? Wg_hh : Wd_ih;
  float* P = (z == 0) ? P0 : (z == 1) ? P1 : P2;
  __shared__ float Xs[64][128];
  float acc[8] = {};
  const int kbeg = split * 256;
  for (int kt = kbeg; kt < kbeg + 256; kt += 128) {
#pragma unroll
    for (int q = 0; q < 8; q++) {
      const int idx = q * 256 + t, r = idx >> 5, c4 = idx & 31;
      const float* xr = (z == 2) ? (emb + (size_t)y[r] * cE)
                                 : ((z == 0) ? (h + (size_t)r * cH)
                                             : (htinit + (size_t)r * cH));
      const float4 v = *(const float4*)(xr + kt + c4 * 4);
      *(float4*)&Xs[r][(c4 ^ (r & 7)) * 4] = v;
    }
    __syncthreads();
    const float* wr[8];
#pragma unroll
    for (int j = 0; j < 8; j++)
      wr[j] = W + (size_t)__builtin_amdgcn_readfirstlane(n0 + j) * K + kt;
#pragma unroll 4
    for (int k = 0; k < 128; k += 4) {
      const float4 xv = *(const float4*)&Xs[lane][(((k >> 2) ^ (lane & 7)) << 2)];
#pragma unroll
      for (int j = 0; j < 8; j++) {
        const float4 wv = *(const float4*)(wr[j] + k);
        acc[j] += xv.x * wv.x + xv.y * wv.y + xv.z * wv.z + xv.w * wv.w;
      }
    }
    __syncthreads();
  }
  float* Pb = P + ((size_t)split * 64 + lane) * cG3;
#pragma unroll
  for (int j = 0; j < 8; j++) Pb[n0 + j] = acc[j];
}

// Generic split-K: grid (N/32, 4). K=1024, chunk 256.
__global__ __launch_bounds__(256) void gemm_sk_kernel(
    const float* __restrict__ X, const float* __restrict__ W,
    float* __restrict__ P, const int N) {
  const int t = threadIdx.x, lane = t & 63, wave = t >> 6;
  const int split = blockIdx.y;
  const int n0 = blockIdx.x * 32 + wave * 8;
  __shared__ float Xs[64][128];
  float acc[8] = {};
  const int kbeg = split * 256;
  for (int kt = kbeg; kt < kbeg + 256; kt += 128) {
#pragma unroll
    for (int q = 0; q < 8; q++) {
      const int idx = q * 256 + t, r = idx >> 5, c4 = idx & 31;
      const float4 v = *(const float4*)(X + (size_t)r * cH + kt + c4 * 4);
      *(float4*)&Xs[r][(c4 ^ (r & 7)) * 4] = v;
    }
    __syncthreads();
    const float* wr[8];
#pragma unroll
    for (int j = 0; j < 8; j++)
      wr[j] = W + (size_t)__builtin_amdgcn_readfirstlane(n0 + j) * cH + kt;
#pragma unroll 4
    for (int k = 0; k < 128; k += 4) {
      const float4 xv = *(const float4*)&Xs[lane][(((k >> 2) ^ (lane & 7)) << 2)];
#pragma unroll
      for (int j = 0; j < 8; j++) {
        const float4 wv = *(const float4*)(wr[j] + k);
        acc[j] += xv.x * wv.x + xv.y * wv.y + xv.z * wv.z + xv.w * wv.w;
      }
    }
    __syncthreads();
  }
  float* Pb = P + ((size_t)split * 64 + lane) * N;
#pragma unroll
  for (int j = 0; j < 8; j++) Pb[n0 + j] = acc[j];
}

// W1 (aspect-masked): grid (32, 2, 8). K=2048, chunk 1024.
__global__ __launch_bounds__(256) void gemm_w1_kernel(
    const float* __restrict__ X, const float* __restrict__ W1,
    const int* __restrict__ aspect_id, float* __restrict__ P) {
  const int t = threadIdx.x, lane = t & 63, wave = t >> 6;
  const int split = blockIdx.y, a = blockIdx.z;
  const int n0 = blockIdx.x * 32 + wave * 8;
  const float* Wa = W1 + (size_t)a * cH * cHM;
  __shared__ float Xs[64][128];
  float acc[8] = {};
  const int kbeg = split * 1024;
  for (int kt = kbeg; kt < kbeg + 1024; kt += 128) {
#pragma unroll
    for (int q = 0; q < 8; q++) {
      const int idx = q * 256 + t, r = idx >> 5, c4 = idx & 31;
      const float4 v = *(const float4*)(X + (size_t)r * cHM + kt + c4 * 4);
      *(float4*)&Xs[r][(c4 ^ (r & 7)) * 4] = v;
    }
    __syncthreads();
    const float* wr[8];
#pragma unroll
    for (int j = 0; j < 8; j++)
      wr[j] = Wa + (size_t)__builtin_amdgcn_readfirstlane(n0 + j) * cHM + kt;
#pragma unroll 4
    for (int k = 0; k < 128; k += 4) {
      const float4 xv = *(const float4*)&Xs[lane][(((k >> 2) ^ (lane & 7)) << 2)];
#pragma unroll
      for (int j = 0; j < 8; j++) {
        const float4 wv = *(const float4*)(wr[j] + k);
        acc[j] += xv.x * wv.x + xv.y * wv.y + xv.z * wv.z + xv.w * wv.w;
      }
    }
    __syncthreads();
  }
  if (aspect_id[lane] != a) return;
  float* Pb = P + ((size_t)split * 64 + lane) * cH;
#pragma unroll
  for (int j = 0; j < 8; j++) Pb[n0 + j] = acc[j];
}

// ------------------------------------------------------------------
// GRU gate kernels, reading split-K partials
// ------------------------------------------------------------------
__global__ __launch_bounds__(256) void gate1_kernel(
    const float* __restrict__ Pi, const float* __restrict__ Ph,
    const float* __restrict__ bih, const float* __restrict__ bhh,
    const float* __restrict__ h_in, const float* __restrict__ hh,
    const int* __restrict__ y, const float* __restrict__ ssin,
    float* __restrict__ h_eff, float* __restrict__ d_sent) {
  const int idx = blockIdx.x * 256 + threadIdx.x;
  const int b = idx >> 10, j = idx & 1023;
  float ir = bih[j], iz = bih[cH + j], in_ = bih[2 * cH + j];
  float hr = bhh[j], hz = bhh[cH + j], hn = bhh[2 * cH + j];
#pragma unroll
  for (int sp = 0; sp < 4; sp++) {
    const float* g = Pi + ((size_t)sp * 64 + b) * cG3;
    ir += g[j]; iz += g[cH + j]; in_ += g[2 * cH + j];
    const float* gg = Ph + ((size_t)sp * 64 + b) * cG3;
    hr += gg[j]; hz += gg[cH + j]; hn += gg[2 * cH + j];
  }
  const float r = sigmf(ir + hr), z = sigmf(iz + hz);
  const float n = tanhf(in_ + r * hn);
  const float hnew = (1.f - z) * n + z * hh[(size_t)b * cH + j];
  const bool peos = (y[b] == PEOS_TOK);
  h_eff[(size_t)b * cH + j] = peos ? hnew : h_in[(size_t)b * cH + j];
  if (j == 0) d_sent[b] = peos ? 1.f : ssin[b];
}

__global__ __launch_bounds__(256) void gate2_kernel(
    const float* __restrict__ Pi, const float* __restrict__ Ph,
    const float* __restrict__ bih, const float* __restrict__ bhh,
    const float* __restrict__ hh, float* __restrict__ h_ws,
    float* __restrict__ h_out) {
  const int idx = blockIdx.x * 256 + threadIdx.x;
  const int b = idx >> 10, j = idx & 1023;
  float ir = bih[j], iz = bih[cH + j], in_ = bih[2 * cH + j];
  float hr = bhh[j], hz = bhh[cH + j], hn = bhh[2 * cH + j];
#pragma unroll
  for (int sp = 0; sp < 2; sp++) {
    const float* g = Pi + ((size_t)sp * 64 + b) * cG3;
    ir += g[j]; iz += g[cH + j]; in_ += g[2 * cH + j];
  }
#pragma unroll
  for (int sp = 0; sp < 4; sp++) {
    const float* gg = Ph + ((size_t)sp * 64 + b) * cG3;
    hr += gg[j]; hz += gg[cH + j]; hn += gg[2 * cH + j];
  }
  const float r = sigmf(ir + hr), z = sigmf(iz + hz);
  const float n = tanhf(in_ + r * hn);
  const float hnew = (1.f - z) * n + z * hh[(size_t)b * cH + j];
  h_ws[(size_t)b * cH + j] = hnew;
  h_out[(size_t)b * cH + j] = hnew;
}

// ------------------------------------------------------------------
// Scores: grid (B, 4). Sums proj partials (+bias) into LDS, computes
// 100 score rows per block, applies mask, writes to ws.
// ------------------------------------------------------------------
__global__ __launch_bounds__(256) void scores_kernel(
    const float* __restrict__ mb, const float* __restrict__ P4,
    const float* __restrict__ attn_b, const float* __restrict__ mask,
    float* __restrict__ scores) {
  const int b = blockIdx.x, t = threadIdx.x, lane = t & 63, wave = t >> 6;
  __shared__ float pr[cM];
  for (int i = t; i < cM; i += 256)
    pr[i] = P4[(size_t)0 * 64 * cM + (size_t)b * cM + i] +
            P4[(size_t)1 * 64 * cM + (size_t)b * cM + i] +
            P4[(size_t)2 * 64 * cM + (size_t)b * cM + i] +
            P4[(size_t)3 * 64 * cM + (size_t)b * cM + i] + attn_b[i];
  __syncthreads();
  float4 p4[4];
#pragma unroll
  for (int j = 0; j < 4; j++) p4[j] = *(const float4*)&pr[j * 256 + lane * 4];
  const int s0 = blockIdx.y * 100;
  const float* mbb = mb + (size_t)b * cS * cM;
  for (int s = s0 + wave; s < s0 + 100; s += 4) {
    const float* row = mbb + (size_t)s * cM;
    float acc = 0.f;
#pragma unroll
    for (int j = 0; j < 4; j++) {
      const float4 v = *(const float4*)(row + j * 256 + lane * 4);
      acc += v.x * p4[j].x + v.y * p4[j].y + v.z * p4[j].z + v.w * p4[j].w;
    }
#pragma unroll
    for (int o = 32; o > 0; o >>= 1) acc += __shfl_xor(acc, o);
    if (lane == 0)
      scores[(size_t)b * cS + s] = (mask[(size_t)b * cS + s] > 0.f) ? acc : -1e9f;
  }
}

// Softmax over S=400 per sample. grid (B), block 256.
__global__ __launch_bounds__(256) void softmax400_kernel(
    const float* __restrict__ scores, float* __restrict__ attn_out) {
  const int b = blockIdx.x, t = threadIdx.x, lane = t & 63, wave = t >> 6;
  __shared__ float sc[cS];
  __shared__ float red[4];
  for (int i = t; i < cS; i += 256) sc[i] = scores[(size_t)b * cS + i];
  __syncthreads();
  float lm = -1e30f;
  for (int i = t; i < cS; i += 256) lm = fmaxf(lm, sc[i]);
#pragma unroll
  for (int o = 32; o > 0; o >>= 1) lm = fmaxf(lm, __shfl_xor(lm, o));
  if (lane == 0) red[wave] = lm;
  __syncthreads();
  const float Mx = fmaxf(fmaxf(red[0], red[1]), fmaxf(red[2], red[3]));
  __syncthreads();
  float ls = 0.f;
  for (int i = t; i < cS; i += 256) { float e = __expf(sc[i] - Mx); sc[i] = e; ls += e; }
#pragma unroll
  for (int o = 32; o > 0; o >>= 1) ls += __shfl_xor(ls, o);
  if (lane == 0) red[wave] = ls;
  __syncthreads();
  const float inv = 1.f / (red[0] + red[1] + red[2] + red[3]);
  for (int i = t; i < cS; i += 256)
    attn_out[(size_t)b * cS + i] = sc[i] * inv;
}

// Context: grid (B, 4), each block 256 contiguous cols. Coalesced mb
// reads, attn broadcast from LDS. Also assembles xcat.
__global__ __launch_bounds__(256) void context_kernel(
    const float* __restrict__ mb, const float* __restrict__ attn,
    const float* __restrict__ h_next, float* __restrict__ d_ctx,
    float* __restrict__ xcat) {
  const int b = blockIdx.x, t = threadIdx.x;
  __shared__ float at[cS];
  for (int i = t; i < cS; i += 256) at[i] = attn[(size_t)b * cS + i];
  __syncthreads();
  const int col = blockIdx.y * 256 + t;
  const float* cp = mb + (size_t)b * cS * cM + col;
  float acc = 0.f;
#pragma unroll 4
  for (int s = 0; s < cS; s++) acc += at[s] * cp[(size_t)s * cM];
  d_ctx[(size_t)b * cM + col] = acc;
  xcat[(size_t)b * cHM + col] = acc;
  xcat[(size_t)b * cHM + cM + col] = h_next[(size_t)b * cH + col];
}

// ------------------------------------------------------------------
// p_gen = sigmoid(pgen_W . [context, h_next, y_emb] + pgen_b)
// ------------------------------------------------------------------
__global__ __launch_bounds__(64) void pgen_kernel(
    const float* __restrict__ xcat, const float* __restrict__ embedding,
    const int* __restrict__ y, const float* __restrict__ pW,
    const float* __restrict__ pb, float* __restrict__ d_pgen,
    float* __restrict__ ws_pgen) {
  const int b = blockIdx.x, l = threadIdx.x;
  float acc = 0.f;
  for (int k = l; k < cHM; k += 64) acc += xcat[(size_t)b * cHM + k] * pW[k];
  const float* er = embedding + (size_t)y[b] * cE;
  for (int k = l; k < cE; k += 64) acc += er[k] * pW[cHM + k];
#pragma unroll
  for (int o = 32; o > 0; o >>= 1) acc += __shfl_xor(acc, o);
  if (l == 0) {
    const float pg = sigmf(acc + pb[0]);
    d_pgen[b] = pg;
    ws_pgen[b] = pg;
  }
}

// ------------------------------------------------------------------
// Logits: subgroup (<=16 samples, one aspect) x 1024 vocab cols/block.
// Stages h1 = P5[0]+P5[1]+b1[a] in LDS (64KB). Last block's cols
// 32000..32767 are masked (val[j]) — W2/b2 reads clamped, stores skipped.
// ------------------------------------------------------------------
__global__ __launch_bounds__(256) void logits_kernel(
    const float* __restrict__ P5, const float* __restrict__ b1,
    const float* __restrict__ W2, const float* __restrict__ b2,
    const int* __restrict__ sgcount, const int* __restrict__ sgaspect,
    const int* __restrict__ sgsamp, float* __restrict__ logits) {
  const int g = blockIdx.y;
  const int ns = sgcount[g];
  if (ns == 0) return;
  const int a = sgaspect[g];
  __shared__ float Xs[16][cH];  // 64 KB
  const int t = threadIdx.x;
  for (int i = t; i < 16 * cH; i += 256) {
    const int s = i >> 10, k = i & (cH - 1);
    const size_t bs = (size_t)sgsamp[g * 16 + s];
    Xs[s][k] = P5[bs * cH + k] + P5[(size_t)64 * cH + bs * cH + k] +
               b1[(size_t)a * cH + k];
  }
  __syncthreads();
  const float* Wa = W2 + (size_t)a * cV * cH;
  const int n0 = blockIdx.x * 1024;
  const float* wp[4];
  bool val[4];
#pragma unroll
  for (int j = 0; j < 4; j++) {
    const int n = n0 + j * 256 + t;
    val[j] = (n < cV);
    wp[j] = Wa + (size_t)(val[j] ? n : 0) * cH;
  }
  float acc[4][16] = {};
#pragma unroll 2
  for (int k = 0; k < cH; k += 4) {
    float4 w[4];
#pragma unroll
    for (int j = 0; j < 4; j++) w[j] = *(const float4*)(wp[j] + k);
#pragma unroll
    for (int s = 0; s < 16; s++) {
      const float4 x = *(const float4*)&Xs[s][k];
#pragma unroll
      for (int j = 0; j < 4; j++)
        acc[j][s] += w[j].x * x.x + w[j].y * x.y + w[j].z * x.z + w[j].w * x.w;
    }
  }
#pragma unroll
  for (int s = 0; s < 16; s++) {
    if (s < ns) {
      const size_t bs = (size_t)sgsamp[g * 16 + s];
#pragma unroll
      for (int j = 0; j < 4; j++)
        if (val[j]) {
          const int n = n0 + j * 256 + t;
          logits[bs * cV + n] = acc[j][s] + b2[(size_t)a * cV + n];
        }
    }
  }
}

// ------------------------------------------------------------------
// Softmax over V, two passes of (B,4) blocks + scatter.
// ------------------------------------------------------------------
__global__ __launch_bounds__(256) void vsm_pass1_kernel(
    const float* __restrict__ logits, float* __restrict__ mpart,
    float* __restrict__ lpart) {
  const int b = blockIdx.x, c = blockIdx.y, t = threadIdx.x;
  const int lane = t & 63, wave = t >> 6;
  __shared__ float red[4];
  const float* lb = logits + (size_t)b * cV + c * 8000;
  float m = -1e30f;
  for (int v = t; v < 8000; v += 256) m = fmaxf(m, lb[v]);
#pragma unroll
  for (int o = 32; o > 0; o >>= 1) m = fmaxf(m, __shfl_xor(m, o));
  if (lane == 0) red[wave] = m;
  __syncthreads();
  const float Mx = fmaxf(fmaxf(red[0], red[1]), fmaxf(red[2], red[3]));
  __syncthreads();
  float l = 0.f;
  for (int v = t; v < 8000; v += 256) l += __expf(lb[v] - Mx);
#pragma unroll
  for (int o = 32; o > 0; o >>= 1) l += __shfl_xor(l, o);
  if (lane == 0) red[wave] = l;
  __syncthreads();
  if (t == 0) {
    mpart[b * 4 + c] = Mx;
    lpart[b * 4 + c] = red[0] + red[1] + red[2] + red[3];
  }
}

__global__ __launch_bounds__(256) void vsm_pass2_kernel(
    float* __restrict__ vocab, float* __restrict__ final_dist,
    const float* __restrict__ mpart, const float* __restrict__ lpart,
    const float* __restrict__ pgen) {
  const int b = blockIdx.x, c = blockIdx.y, t = threadIdx.x;
  const float m0 = mpart[b * 4 + 0], m1 = mpart[b * 4 + 1];
  const float m2 = mpart[b * 4 + 2], m3 = mpart[b * 4 + 3];
  const float Mx = fmaxf(fmaxf(m0, m1), fmaxf(m2, m3));
  const float L = lpart[b * 4 + 0] * __expf(m0 - Mx) +
                  lpart[b * 4 + 1] * __expf(m1 - Mx) +
                  lpart[b * 4 + 2] * __expf(m2 - Mx) +
                  lpart[b * 4 + 3] * __expf(m3 - Mx);
  const float inv = 1.f / L;
  const float pg = pgen[b];
  float* vb = vocab + (size_t)b * cV + c * 8000;
  float* fb = final_dist + (size_t)b * cV + c * 8000;
  for (int v = t; v < 8000; v += 256) {
    const float e = __expf(vb[v] - Mx) * inv;
    vb[v] = e;
    fb[v] = pg * e;
  }
}

__global__ __launch_bounds__(256) void scatter_kernel(
    float* __restrict__ final_dist, const float* __restrict__ pgen,
    const float* __restrict__ attn, const int* __restrict__ src) {
  const int b = blockIdx.x, t = threadIdx.x;
  const float cp = 1.f - pgen[b];
  float* fb = final_dist + (size_t)b * cV;
  for (int s = t; s < cS; s += 256)
    atomicAdd(fb + src[(size_t)b * cS + s], cp * attn[(size_t)b * cS + s]);
}

// ------------------------------------------------------------------
extern "C" void kernel_launch(void* const* d_in, const int* in_sizes, int n_in,
                              void* d_out, int out_size, void* d_ws, size_t ws_size,
                              hipStream_t stream) {
  const int*   y      = (const int*)d_in[0];
  const float* h      = (const float*)d_in[1];
  const float* mb     = (const float*)d_in[2];
  const float* mask   = (const float*)d_in[3];
  const int*   src    = (const int*)d_in[4];
  const int*   aspect = (const int*)d_in[5];
  const float* htinit = (const float*)d_in[7];
  const float* ssin   = (const float*)d_in[8];
  const float* cov    = (const float*)d_in[9];
  const float* wah    = (const float*)d_in[10];
  const float* emb    = (const float*)d_in[11];
  const float* gWih   = (const float*)d_in[12];
  const float* gWhh   = (const float*)d_in[13];
  const float* gbih   = (const float*)d_in[14];
  const float* gbhh   = (const float*)d_in[15];
  const float* ggWih  = (const float*)d_in[16];
  const float* ggWhh  = (const float*)d_in[17];
  const float* ggbih  = (const float*)d_in[18];
  const float* ggbhh  = (const float*)d_in[19];
  const float* attnW  = (const float*)d_in[20];
  const float* attnb  = (const float*)d_in[21];
  const float* pW     = (const float*)d_in[22];
  const float* pb     = (const float*)d_in[23];
  const float* W1     = (const float*)d_in[24];
  const float* b1     = (const float*)d_in[25];
  const float* W2     = (const float*)d_in[26];
  const float* b2     = (const float*)d_in[27];

  float* out = (float*)d_out;
  float* ws  = (float*)d_ws;
  int* sg       = (int*)(ws + WS_SG);
  int* sgcount  = sg;
  int* sgaspect = sg + MAXSG;
  int* sgsamp   = sg + 2 * MAXSG;

  // 0) aspect subgrouping
  group_kernel<<<1, 64, 0, stream>>>(aspect, sgcount, sgaspect, sgsamp);
  // 1) three independent input GEMMs (gi_g, gh_g, gi_d), split-K
  gemm3_kernel<<<dim3(cG3 / 32, 4, 3), 256, 0, stream>>>(
      h, htinit, emb, y, ggWih, ggWhh, gWih,
      ws + WS_P0, ws + WS_P1, ws + WS_P2);
  gate1_kernel<<<cB * cH / 256, 256, 0, stream>>>(
      ws + WS_P0, ws + WS_P1, ggbih, ggbhh, h, htinit, y, ssin,
      ws + WS_HEFF, out + O_SENT);
  // 2) gh_d = h_eff @ gru_W_hh^T
  gemm_sk_kernel<<<dim3(cG3 / 32, 4), 256, 0, stream>>>(
      ws + WS_HEFF, gWhh, ws + WS_P3, cG3);
  gate2_kernel<<<cB * cH / 256, 256, 0, stream>>>(
      ws + WS_P2, ws + WS_P3, gbih, gbhh, ws + WS_HEFF,
      ws + WS_HNEXT, out + O_HNEXT);
  // 3) attention
  gemm_sk_kernel<<<dim3(cM / 32, 4), 256, 0, stream>>>(
      ws + WS_HNEXT, attnW, ws + WS_P4, cM);
  scores_kernel<<<dim3(cB, 4), 256, 0, stream>>>(
      mb, ws + WS_P4, attnb, mask, ws + WS_SCORE);
  softmax400_kernel<<<cB, 256, 0, stream>>>(ws + WS_SCORE, out + O_ATTN);
  context_kernel<<<dim3(cB, 4), 256, 0, stream>>>(
      mb, out + O_ATTN, ws + WS_HNEXT, out + O_CTX, ws + WS_XCAT);
  pgen_kernel<<<cB, 64, 0, stream>>>(ws + WS_XCAT, emb, y, pW, pb,
                                     out + O_PGEN, ws + WS_PGEN);
  // 4) aspect head
  gemm_w1_kernel<<<dim3(cH / 32, 2, cA), 256, 0, stream>>>(
      ws + WS_XCAT, W1, aspect, ws + WS_P5);
  logits_kernel<<<dim3(32, MAXSG), 256, 0, stream>>>(
      ws + WS_P5, b1, W2, b2, sgcount, sgaspect, sgsamp, out + O_VOCAB);
  // 5) softmax over V + copy gate + pointer scatter
  vsm_pass1_kernel<<<dim3(cB, 4), 256, 0, stream>>>(
      out + O_VOCAB, ws + WS_MPART, ws + WS_LPART);
  vsm_pass2_kernel<<<dim3(cB, 4), 256, 0, stream>>>(
      out + O_VOCAB, out + O_FINAL, ws + WS_MPART, ws + WS_LPART, ws + WS_PGEN);
  scatter_kernel<<<cB, 256, 0, stream>>>(out + O_FINAL, ws + WS_PGEN,
                                         out + O_ATTN, src);
  // 6) passthrough outputs
  hipMemcpyAsync(out + O_COV, cov, (size_t)cB * cS * sizeof(float),
                 hipMemcpyDeviceToDevice, stream);
  hipMemcpyAsync(out + O_WAH, wah, (size_t)cB * cM * sizeof(float),
                 hipMemcpyDeviceToDevice, stream);
}

// Round 4
// 806.913 us; speedup vs baseline: 1.7603x; 1.1874x over previous
//
#include <hip/hip_runtime.h>
#include <math.h>

// Problem constants (HiRNNDecoder)
constexpr int cB = 64, cS = 400, cH = 1024, cM = 1024, cE = 512, cV = 32000, cA = 8;
constexpr int cHM = cH + cM;   // 2048
constexpr int cG3 = 3 * cH;    // 3072
constexpr int PEOS_TOK = 4;
constexpr int MAXSG = 12;

// ---- workspace layout (float offsets) ----
constexpr size_t WS_P0    = 0;                               // gi_g parts [4][64][3072]
constexpr size_t WS_P1    = WS_P0 + (size_t)4 * cB * cG3;    // gh_g parts [4][64][3072]
constexpr size_t WS_P2    = WS_P1 + (size_t)4 * cB * cG3;    // gi_d parts [2][64][3072]
constexpr size_t WS_P3    = WS_P2 + (size_t)2 * cB * cG3;    // gh_d parts [4][64][3072]
constexpr size_t WS_P4    = WS_P3 + (size_t)4 * cB * cG3;    // proj parts [4][64][1024]
constexpr size_t WS_P5    = WS_P4 + (size_t)4 * cB * cM;     // h1 parts [2][64][1024]
constexpr size_t WS_HEFF  = WS_P5 + (size_t)2 * cB * cH;
constexpr size_t WS_HNEXT = WS_HEFF + (size_t)cB * cH;
constexpr size_t WS_XCAT  = WS_HNEXT + (size_t)cB * cH;
constexpr size_t WS_SCORE = WS_XCAT + (size_t)cB * cHM;
constexpr size_t WS_PGEN  = WS_SCORE + (size_t)cB * cS;
constexpr size_t WS_MPART = WS_PGEN + cB;
constexpr size_t WS_LPART = WS_MPART + (size_t)cB * 4;
constexpr size_t WS_SG    = WS_LPART + (size_t)cB * 4;       // int region

// ---- output layout (float offsets, reference return order) ----
constexpr size_t O_VOCAB = 0;
constexpr size_t O_FINAL = O_VOCAB + (size_t)cB * cV;
constexpr size_t O_HNEXT = O_FINAL + (size_t)cB * cV;
constexpr size_t O_CTX   = O_HNEXT + (size_t)cB * cH;
constexpr size_t O_ATTN  = O_CTX + (size_t)cB * cM;
constexpr size_t O_PGEN  = O_ATTN + (size_t)cB * cS;
constexpr size_t O_COV   = O_PGEN + cB;
constexpr size_t O_SENT  = O_COV + (size_t)cB * cS;
constexpr size_t O_WAH   = O_SENT + cB;

__device__ __forceinline__ float sigmf(float x) { return 1.f / (1.f + __expf(-x)); }

// ------------------------------------------------------------------
// K0: bucket samples by aspect into subgroups of <=16
// ------------------------------------------------------------------
__global__ void group_kernel(const int* __restrict__ aspect_id,
                             int* __restrict__ sgcount, int* __restrict__ sgaspect,
                             int* __restrict__ sgsamp) {
  if (threadIdx.x != 0 || blockIdx.x != 0) return;
  int cnt[cA];
  int lists[cA][cB];
  for (int a = 0; a < cA; a++) cnt[a] = 0;
  for (int b = 0; b < cB; b++) { int a = aspect_id[b]; lists[a][cnt[a]++] = b; }
  int g = 0;
  for (int a = 0; a < cA; a++) {
    for (int off = 0; off < cnt[a]; off += 16) {
      int c = cnt[a] - off; if (c > 16) c = 16;
      sgcount[g] = c; sgaspect[g] = a;
      for (int i = 0; i < 16; i++) sgsamp[g * 16 + i] = lists[a][off + (i < c ? i : 0)];
      g++;
    }
  }
  for (; g < MAXSG; g++) sgcount[g] = 0;
}

// ==================================================================
// Split-K skinny GEMM core: 64 samples (lane), 32 cols/block (8/wave),
// one 256-wide K chunk per blockIdx.y. X tile XOR-swizzled in LDS so
// the per-lane ds_read_b128 is conflict-free; W row pointers hoisted
// via readfirstlane (wave-uniform -> scalar-load candidates).
// ==================================================================

// Merged input GEMMs: z=0 gi_g (h @ gWih_g^T), z=1 gh_g (htinit @ gWhh_g^T),
// z=2 gi_d (emb[y] @ gWih_d^T, K=512, 2 splits). grid (96, 4, 3).
__global__ __launch_bounds__(256) void gemm3_kernel(
    const float* __restrict__ h, const float* __restrict__ htinit,
    const float* __restrict__ emb, const int* __restrict__ y,
    const float* __restrict__ Wg_ih, const float* __restrict__ Wg_hh,
    const float* __restrict__ Wd_ih,
    float* __restrict__ P0, float* __restrict__ P1, float* __restrict__ P2) {
  const int z = blockIdx.z, split = blockIdx.y;
  if (z == 2 && split >= 2) return;
  const int t = threadIdx.x, lane = t & 63, wave = t >> 6;
  const int n0 = blockIdx.x * 32 + wave * 8;
  const int K = (z == 2) ? cE : cH;
  const float* W = (z == 0) ? Wg_ih : (z == 1) ? Wg_hh : Wd_ih;
  float* P = (z == 0) ? P0 : (z == 1) ? P1 : P2;
  __shared__ float Xs[64][128];
  float acc[8] = {};
  const int kbeg = split * 256;
  for (int kt = kbeg; kt < kbeg + 256; kt += 128) {
#pragma unroll
    for (int q = 0; q < 8; q++) {
      const int idx = q * 256 + t, r = idx >> 5, c4 = idx & 31;
      const float* xr = (z == 2) ? (emb + (size_t)y[r] * cE)
                                 : ((z == 0) ? (h + (size_t)r * cH)
                                             : (htinit + (size_t)r * cH));
      const float4 v = *(const float4*)(xr + kt + c4 * 4);
      *(float4*)&Xs[r][(c4 ^ (r & 7)) * 4] = v;
    }
    __syncthreads();
    const float* wr[8];
#pragma unroll
    for (int j = 0; j < 8; j++)
      wr[j] = W + (size_t)__builtin_amdgcn_readfirstlane(n0 + j) * K + kt;
#pragma unroll 4
    for (int k = 0; k < 128; k += 4) {
      const float4 xv = *(const float4*)&Xs[lane][(((k >> 2) ^ (lane & 7)) << 2)];
#pragma unroll
      for (int j = 0; j < 8; j++) {
        const float4 wv = *(const float4*)(wr[j] + k);
        acc[j] += xv.x * wv.x + xv.y * wv.y + xv.z * wv.z + xv.w * wv.w;
      }
    }
    __syncthreads();
  }
  float* Pb = P + ((size_t)split * 64 + lane) * cG3;
#pragma unroll
  for (int j = 0; j < 8; j++) Pb[n0 + j] = acc[j];
}

// Generic split-K: grid (N/32, 4). K=1024, chunk 256.
__global__ __launch_bounds__(256) void gemm_sk_kernel(
    const float* __restrict__ X, const float* __restrict__ W,
    float* __restrict__ P, const int N) {
  const int t = threadIdx.x, lane = t & 63, wave = t >> 6;
  const int split = blockIdx.y;
  const int n0 = blockIdx.x * 32 + wave * 8;
  __shared__ float Xs[64][128];
  float acc[8] = {};
  const int kbeg = split * 256;
  for (int kt = kbeg; kt < kbeg + 256; kt += 128) {
#pragma unroll
    for (int q = 0; q < 8; q++) {
      const int idx = q * 256 + t, r = idx >> 5, c4 = idx & 31;
      const float4 v = *(const float4*)(X + (size_t)r * cH + kt + c4 * 4);
      *(float4*)&Xs[r][(c4 ^ (r & 7)) * 4] = v;
    }
    __syncthreads();
    const float* wr[8];
#pragma unroll
    for (int j = 0; j < 8; j++)
      wr[j] = W + (size_t)__builtin_amdgcn_readfirstlane(n0 + j) * cH + kt;
#pragma unroll 4
    for (int k = 0; k < 128; k += 4) {
      const float4 xv = *(const float4*)&Xs[lane][(((k >> 2) ^ (lane & 7)) << 2)];
#pragma unroll
      for (int j = 0; j < 8; j++) {
        const float4 wv = *(const float4*)(wr[j] + k);
        acc[j] += xv.x * wv.x + xv.y * wv.y + xv.z * wv.z + xv.w * wv.w;
      }
    }
    __syncthreads();
  }
  float* Pb = P + ((size_t)split * 64 + lane) * N;
#pragma unroll
  for (int j = 0; j < 8; j++) Pb[n0 + j] = acc[j];
}

// W1 (aspect-masked): grid (32, 2, 8). K=2048, chunk 1024.
__global__ __launch_bounds__(256) void gemm_w1_kernel(
    const float* __restrict__ X, const float* __restrict__ W1,
    const int* __restrict__ aspect_id, float* __restrict__ P) {
  const int t = threadIdx.x, lane = t & 63, wave = t >> 6;
  const int split = blockIdx.y, a = blockIdx.z;
  const int n0 = blockIdx.x * 32 + wave * 8;
  const float* Wa = W1 + (size_t)a * cH * cHM;
  __shared__ float Xs[64][128];
  float acc[8] = {};
  const int kbeg = split * 1024;
  for (int kt = kbeg; kt < kbeg + 1024; kt += 128) {
#pragma unroll
    for (int q = 0; q < 8; q++) {
      const int idx = q * 256 + t, r = idx >> 5, c4 = idx & 31;
      const float4 v = *(const float4*)(X + (size_t)r * cHM + kt + c4 * 4);
      *(float4*)&Xs[r][(c4 ^ (r & 7)) * 4] = v;
    }
    __syncthreads();
    const float* wr[8];
#pragma unroll
    for (int j = 0; j < 8; j++)
      wr[j] = Wa + (size_t)__builtin_amdgcn_readfirstlane(n0 + j) * cHM + kt;
#pragma unroll 4
    for (int k = 0; k < 128; k += 4) {
      const float4 xv = *(const float4*)&Xs[lane][(((k >> 2) ^ (lane & 7)) << 2)];
#pragma unroll
      for (int j = 0; j < 8; j++) {
        const float4 wv = *(const float4*)(wr[j] + k);
        acc[j] += xv.x * wv.x + xv.y * wv.y + xv.z * wv.z + xv.w * wv.w;
      }
    }
    __syncthreads();
  }
  if (aspect_id[lane] != a) return;
  float* Pb = P + ((size_t)split * 64 + lane) * cH;
#pragma unroll
  for (int j = 0; j < 8; j++) Pb[n0 + j] = acc[j];
}

// ------------------------------------------------------------------
// GRU gate kernels, reading split-K partials
// ------------------------------------------------------------------
__global__ __launch_bounds__(256) void gate1_kernel(
    const float* __restrict__ Pi, const float* __restrict__ Ph,
    const float* __restrict__ bih, const float* __restrict__ bhh,
    const float* __restrict__ h_in, const float* __restrict__ hh,
    const int* __restrict__ y, const float* __restrict__ ssin,
    float* __restrict__ h_eff, float* __restrict__ d_sent) {
  const int idx = blockIdx.x * 256 + threadIdx.x;
  const int b = idx >> 10, j = idx & 1023;
  float ir = bih[j], iz = bih[cH + j], in_ = bih[2 * cH + j];
  float hr = bhh[j], hz = bhh[cH + j], hn = bhh[2 * cH + j];
#pragma unroll
  for (int sp = 0; sp < 4; sp++) {
    const float* g = Pi + ((size_t)sp * 64 + b) * cG3;
    ir += g[j]; iz += g[cH + j]; in_ += g[2 * cH + j];
    const float* gg = Ph + ((size_t)sp * 64 + b) * cG3;
    hr += gg[j]; hz += gg[cH + j]; hn += gg[2 * cH + j];
  }
  const float r = sigmf(ir + hr), z = sigmf(iz + hz);
  const float n = tanhf(in_ + r * hn);
  const float hnew = (1.f - z) * n + z * hh[(size_t)b * cH + j];
  const bool peos = (y[b] == PEOS_TOK);
  h_eff[(size_t)b * cH + j] = peos ? hnew : h_in[(size_t)b * cH + j];
  if (j == 0) d_sent[b] = peos ? 1.f : ssin[b];
}

__global__ __launch_bounds__(256) void gate2_kernel(
    const float* __restrict__ Pi, const float* __restrict__ Ph,
    const float* __restrict__ bih, const float* __restrict__ bhh,
    const float* __restrict__ hh, float* __restrict__ h_ws,
    float* __restrict__ h_out) {
  const int idx = blockIdx.x * 256 + threadIdx.x;
  const int b = idx >> 10, j = idx & 1023;
  float ir = bih[j], iz = bih[cH + j], in_ = bih[2 * cH + j];
  float hr = bhh[j], hz = bhh[cH + j], hn = bhh[2 * cH + j];
#pragma unroll
  for (int sp = 0; sp < 2; sp++) {
    const float* g = Pi + ((size_t)sp * 64 + b) * cG3;
    ir += g[j]; iz += g[cH + j]; in_ += g[2 * cH + j];
  }
#pragma unroll
  for (int sp = 0; sp < 4; sp++) {
    const float* gg = Ph + ((size_t)sp * 64 + b) * cG3;
    hr += gg[j]; hz += gg[cH + j]; hn += gg[2 * cH + j];
  }
  const float r = sigmf(ir + hr), z = sigmf(iz + hz);
  const float n = tanhf(in_ + r * hn);
  const float hnew = (1.f - z) * n + z * hh[(size_t)b * cH + j];
  h_ws[(size_t)b * cH + j] = hnew;
  h_out[(size_t)b * cH + j] = hnew;
}

// ------------------------------------------------------------------
// Scores: grid (B, 4). Sums proj partials (+bias) into LDS, computes
// 100 score rows per block, applies mask, writes to ws.
// ------------------------------------------------------------------
__global__ __launch_bounds__(256) void scores_kernel(
    const float* __restrict__ mb, const float* __restrict__ P4,
    const float* __restrict__ attn_b, const float* __restrict__ mask,
    float* __restrict__ scores) {
  const int b = blockIdx.x, t = threadIdx.x, lane = t & 63, wave = t >> 6;
  __shared__ float pr[cM];
  for (int i = t; i < cM; i += 256)
    pr[i] = P4[(size_t)0 * 64 * cM + (size_t)b * cM + i] +
            P4[(size_t)1 * 64 * cM + (size_t)b * cM + i] +
            P4[(size_t)2 * 64 * cM + (size_t)b * cM + i] +
            P4[(size_t)3 * 64 * cM + (size_t)b * cM + i] + attn_b[i];
  __syncthreads();
  float4 p4[4];
#pragma unroll
  for (int j = 0; j < 4; j++) p4[j] = *(const float4*)&pr[j * 256 + lane * 4];
  const int s0 = blockIdx.y * 100;
  const float* mbb = mb + (size_t)b * cS * cM;
  for (int s = s0 + wave; s < s0 + 100; s += 4) {
    const float* row = mbb + (size_t)s * cM;
    float acc = 0.f;
#pragma unroll
    for (int j = 0; j < 4; j++) {
      const float4 v = *(const float4*)(row + j * 256 + lane * 4);
      acc += v.x * p4[j].x + v.y * p4[j].y + v.z * p4[j].z + v.w * p4[j].w;
    }
#pragma unroll
    for (int o = 32; o > 0; o >>= 1) acc += __shfl_xor(acc, o);
    if (lane == 0)
      scores[(size_t)b * cS + s] = (mask[(size_t)b * cS + s] > 0.f) ? acc : -1e9f;
  }
}

// Softmax over S=400 per sample. grid (B), block 256.
__global__ __launch_bounds__(256) void softmax400_kernel(
    const float* __restrict__ scores, float* __restrict__ attn_out) {
  const int b = blockIdx.x, t = threadIdx.x, lane = t & 63, wave = t >> 6;
  __shared__ float sc[cS];
  __shared__ float red[4];
  for (int i = t; i < cS; i += 256) sc[i] = scores[(size_t)b * cS + i];
  __syncthreads();
  float lm = -1e30f;
  for (int i = t; i < cS; i += 256) lm = fmaxf(lm, sc[i]);
#pragma unroll
  for (int o = 32; o > 0; o >>= 1) lm = fmaxf(lm, __shfl_xor(lm, o));
  if (lane == 0) red[wave] = lm;
  __syncthreads();
  const float Mx = fmaxf(fmaxf(red[0], red[1]), fmaxf(red[2], red[3]));
  __syncthreads();
  float ls = 0.f;
  for (int i = t; i < cS; i += 256) { float e = __expf(sc[i] - Mx); sc[i] = e; ls += e; }
#pragma unroll
  for (int o = 32; o > 0; o >>= 1) ls += __shfl_xor(ls, o);
  if (lane == 0) red[wave] = ls;
  __syncthreads();
  const float inv = 1.f / (red[0] + red[1] + red[2] + red[3]);
  for (int i = t; i < cS; i += 256)
    attn_out[(size_t)b * cS + i] = sc[i] * inv;
}

// Context: grid (B, 4), each block 256 contiguous cols. Coalesced mb
// reads, attn broadcast from LDS. Also assembles xcat.
__global__ __launch_bounds__(256) void context_kernel(
    const float* __restrict__ mb, const float* __restrict__ attn,
    const float* __restrict__ h_next, float* __restrict__ d_ctx,
    float* __restrict__ xcat) {
  const int b = blockIdx.x, t = threadIdx.x;
  __shared__ float at[cS];
  for (int i = t; i < cS; i += 256) at[i] = attn[(size_t)b * cS + i];
  __syncthreads();
  const int col = blockIdx.y * 256 + t;
  const float* cp = mb + (size_t)b * cS * cM + col;
  float acc = 0.f;
#pragma unroll 4
  for (int s = 0; s < cS; s++) acc += at[s] * cp[(size_t)s * cM];
  d_ctx[(size_t)b * cM + col] = acc;
  xcat[(size_t)b * cHM + col] = acc;
  xcat[(size_t)b * cHM + cM + col] = h_next[(size_t)b * cH + col];
}

// ------------------------------------------------------------------
// p_gen = sigmoid(pgen_W . [context, h_next, y_emb] + pgen_b)
// ------------------------------------------------------------------
__global__ __launch_bounds__(64) void pgen_kernel(
    const float* __restrict__ xcat, const float* __restrict__ embedding,
    const int* __restrict__ y, const float* __restrict__ pW,
    const float* __restrict__ pb, float* __restrict__ d_pgen,
    float* __restrict__ ws_pgen) {
  const int b = blockIdx.x, l = threadIdx.x;
  float acc = 0.f;
  for (int k = l; k < cHM; k += 64) acc += xcat[(size_t)b * cHM + k] * pW[k];
  const float* er = embedding + (size_t)y[b] * cE;
  for (int k = l; k < cE; k += 64) acc += er[k] * pW[cHM + k];
#pragma unroll
  for (int o = 32; o > 0; o >>= 1) acc += __shfl_xor(acc, o);
  if (l == 0) {
    const float pg = sigmf(acc + pb[0]);
    d_pgen[b] = pg;
    ws_pgen[b] = pg;
  }
}

// ------------------------------------------------------------------
// Logits: subgroup (<=16 samples, one aspect) x 512 vocab rows/block.
// Each thread owns 2 rows (t, t+256) and consumes a FULL 128B line of
// each row per k-iteration (k-step 32, 8xfloat4 in regs) -> every W2
// cache line is fetched once and fully used within the iteration; no
// dependence on L1/L2 retention. h1 = P5[0]+P5[1]+b1[a] staged in LDS;
// Xs reads are lane-uniform broadcasts (conflict-free).
// ------------------------------------------------------------------
__global__ __launch_bounds__(256) void logits_kernel(
    const float* __restrict__ P5, const float* __restrict__ b1,
    const float* __restrict__ W2, const float* __restrict__ b2,
    const int* __restrict__ sgcount, const int* __restrict__ sgaspect,
    const int* __restrict__ sgsamp, float* __restrict__ logits) {
  const int g = blockIdx.y;
  const int ns = sgcount[g];
  if (ns == 0) return;
  const int a = sgaspect[g];
  __shared__ float Xs[16][cH];  // 64 KB
  const int t = threadIdx.x;
  for (int i = t; i < 16 * cH; i += 256) {
    const int s = i >> 10, k = i & (cH - 1);
    const size_t bs = (size_t)sgsamp[g * 16 + s];
    Xs[s][k] = P5[bs * cH + k] + P5[(size_t)64 * cH + bs * cH + k] +
               b1[(size_t)a * cH + k];
  }
  __syncthreads();
  const float* Wa = W2 + (size_t)a * cV * cH;
  const int n0 = blockIdx.x * 512;
  const int r0 = n0 + t, r1 = n0 + 256 + t;
  if (r0 >= cV) return;
  const bool v1 = (r1 < cV);
  const float* wp0 = Wa + (size_t)r0 * cH;
  const float* wp1 = Wa + (size_t)(v1 ? r1 : r0) * cH;
  float acc0[16] = {}, acc1[16] = {};
  for (int k = 0; k < cH; k += 32) {
    float4 w0[8], w1[8];
#pragma unroll
    for (int q = 0; q < 8; q++) {
      w0[q] = *(const float4*)(wp0 + k + q * 4);
      w1[q] = *(const float4*)(wp1 + k + q * 4);
    }
#pragma unroll
    for (int s = 0; s < 16; s++) {
      float a0 = 0.f, a1 = 0.f;
#pragma unroll
      for (int q = 0; q < 8; q++) {
        const float4 x = *(const float4*)&Xs[s][k + q * 4];
        a0 += w0[q].x * x.x + w0[q].y * x.y + w0[q].z * x.z + w0[q].w * x.w;
        a1 += w1[q].x * x.x + w1[q].y * x.y + w1[q].z * x.z + w1[q].w * x.w;
      }
      acc0[s] += a0; acc1[s] += a1;
    }
  }
  const float bb0 = b2[(size_t)a * cV + r0];
  const float bb1 = v1 ? b2[(size_t)a * cV + r1] : 0.f;
  for (int s = 0; s < ns; s++) {
    const size_t bs = (size_t)sgsamp[g * 16 + s];
    logits[bs * cV + r0] = acc0[s] + bb0;
    if (v1) logits[bs * cV + r1] = acc1[s] + bb1;
  }
}

// ------------------------------------------------------------------
// Softmax over V, two passes of (B,4) blocks + scatter.
// ------------------------------------------------------------------
__global__ __launch_bounds__(256) void vsm_pass1_kernel(
    const float* __restrict__ logits, float* __restrict__ mpart,
    float* __restrict__ lpart) {
  const int b = blockIdx.x, c = blockIdx.y, t = threadIdx.x;
  const int lane = t & 63, wave = t >> 6;
  __shared__ float red[4];
  const float* lb = logits + (size_t)b * cV + c * 8000;
  float m = -1e30f;
  for (int v = t; v < 8000; v += 256) m = fmaxf(m, lb[v]);
#pragma unroll
  for (int o = 32; o > 0; o >>= 1) m = fmaxf(m, __shfl_xor(m, o));
  if (lane == 0) red[wave] = m;
  __syncthreads();
  const float Mx = fmaxf(fmaxf(red[0], red[1]), fmaxf(red[2], red[3]));
  __syncthreads();
  float l = 0.f;
  for (int v = t; v < 8000; v += 256) l += __expf(lb[v] - Mx);
#pragma unroll
  for (int o = 32; o > 0; o >>= 1) l += __shfl_xor(l, o);
  if (lane == 0) red[wave] = l;
  __syncthreads();
  if (t == 0) {
    mpart[b * 4 + c] = Mx;
    lpart[b * 4 + c] = red[0] + red[1] + red[2] + red[3];
  }
}

__global__ __launch_bounds__(256) void vsm_pass2_kernel(
    float* __restrict__ vocab, float* __restrict__ final_dist,
    const float* __restrict__ mpart, const float* __restrict__ lpart,
    const float* __restrict__ pgen) {
  const int b = blockIdx.x, c = blockIdx.y, t = threadIdx.x;
  const float m0 = mpart[b * 4 + 0], m1 = mpart[b * 4 + 1];
  const float m2 = mpart[b * 4 + 2], m3 = mpart[b * 4 + 3];
  const float Mx = fmaxf(fmaxf(m0, m1), fmaxf(m2, m3));
  const float L = lpart[b * 4 + 0] * __expf(m0 - Mx) +
                  lpart[b * 4 + 1] * __expf(m1 - Mx) +
                  lpart[b * 4 + 2] * __expf(m2 - Mx) +
                  lpart[b * 4 + 3] * __expf(m3 - Mx);
  const float inv = 1.f / L;
  const float pg = pgen[b];
  float* vb = vocab + (size_t)b * cV + c * 8000;
  float* fb = final_dist + (size_t)b * cV + c * 8000;
  for (int v = t; v < 8000; v += 256) {
    const float e = __expf(vb[v] - Mx) * inv;
    vb[v] = e;
    fb[v] = pg * e;
  }
}

__global__ __launch_bounds__(256) void scatter_kernel(
    float* __restrict__ final_dist, const float* __restrict__ pgen,
    const float* __restrict__ attn, const int* __restrict__ src) {
  const int b = blockIdx.x, t = threadIdx.x;
  const float cp = 1.f - pgen[b];
  float* fb = final_dist + (size_t)b * cV;
  for (int s = t; s < cS; s += 256)
    atomicAdd(fb + src[(size_t)b * cS + s], cp * attn[(size_t)b * cS + s]);
}

// ------------------------------------------------------------------
extern "C" void kernel_launch(void* const* d_in, const int* in_sizes, int n_in,
                              void* d_out, int out_size, void* d_ws, size_t ws_size,
                              hipStream_t stream) {
  const int*   y      = (const int*)d_in[0];
  const float* h      = (const float*)d_in[1];
  const float* mb     = (const float*)d_in[2];
  const float* mask   = (const float*)d_in[3];
  const int*   src    = (const int*)d_in[4];
  const int*   aspect = (const int*)d_in[5];
  const float* htinit = (const float*)d_in[7];
  const float* ssin   = (const float*)d_in[8];
  const float* cov    = (const float*)d_in[9];
  const float* wah    = (const float*)d_in[10];
  const float* emb    = (const float*)d_in[11];
  const float* gWih   = (const float*)d_in[12];
  const float* gWhh   = (const float*)d_in[13];
  const float* gbih   = (const float*)d_in[14];
  const float* gbhh   = (const float*)d_in[15];
  const float* ggWih  = (const float*)d_in[16];
  const float* ggWhh  = (const float*)d_in[17];
  const float* ggbih  = (const float*)d_in[18];
  const float* ggbhh  = (const float*)d_in[19];
  const float* attnW  = (const float*)d_in[20];
  const float* attnb  = (const float*)d_in[21];
  const float* pW     = (const float*)d_in[22];
  const float* pb     = (const float*)d_in[23];
  const float* W1     = (const float*)d_in[24];
  const float* b1     = (const float*)d_in[25];
  const float* W2     = (const float*)d_in[26];
  const float* b2     = (const float*)d_in[27];

  float* out = (float*)d_out;
  float* ws  = (float*)d_ws;
  int* sg       = (int*)(ws + WS_SG);
  int* sgcount  = sg;
  int* sgaspect = sg + MAXSG;
  int* sgsamp   = sg + 2 * MAXSG;

  // 0) aspect subgrouping
  group_kernel<<<1, 64, 0, stream>>>(aspect, sgcount, sgaspect, sgsamp);
  // 1) three independent input GEMMs (gi_g, gh_g, gi_d), split-K
  gemm3_kernel<<<dim3(cG3 / 32, 4, 3), 256, 0, stream>>>(
      h, htinit, emb, y, ggWih, ggWhh, gWih,
      ws + WS_P0, ws + WS_P1, ws + WS_P2);
  gate1_kernel<<<cB * cH / 256, 256, 0, stream>>>(
      ws + WS_P0, ws + WS_P1, ggbih, ggbhh, h, htinit, y, ssin,
      ws + WS_HEFF, out + O_SENT);
  // 2) gh_d = h_eff @ gru_W_hh^T
  gemm_sk_kernel<<<dim3(cG3 / 32, 4), 256, 0, stream>>>(
      ws + WS_HEFF, gWhh, ws + WS_P3, cG3);
  gate2_kernel<<<cB * cH / 256, 256, 0, stream>>>(
      ws + WS_P2, ws + WS_P3, gbih, gbhh, ws + WS_HEFF,
      ws + WS_HNEXT, out + O_HNEXT);
  // 3) attention
  gemm_sk_kernel<<<dim3(cM / 32, 4), 256, 0, stream>>>(
      ws + WS_HNEXT, attnW, ws + WS_P4, cM);
  scores_kernel<<<dim3(cB, 4), 256, 0, stream>>>(
      mb, ws + WS_P4, attnb, mask, ws + WS_SCORE);
  softmax400_kernel<<<cB, 256, 0, stream>>>(ws + WS_SCORE, out + O_ATTN);
  context_kernel<<<dim3(cB, 4), 256, 0, stream>>>(
      mb, out + O_ATTN, ws + WS_HNEXT, out + O_CTX, ws + WS_XCAT);
  pgen_kernel<<<cB, 64, 0, stream>>>(ws + WS_XCAT, emb, y, pW, pb,
                                     out + O_PGEN, ws + WS_PGEN);
  // 4) aspect head
  gemm_w1_kernel<<<dim3(cH / 32, 2, cA), 256, 0, stream>>>(
      ws + WS_XCAT, W1, aspect, ws + WS_P5);
  logits_kernel<<<dim3((cV + 511) / 512, MAXSG), 256, 0, stream>>>(
      ws + WS_P5, b1, W2, b2, sgcount, sgaspect, sgsamp, out + O_VOCAB);
  // 5) softmax over V + copy gate + pointer scatter
  vsm_pass1_kernel<<<dim3(cB, 4), 256, 0, stream>>>(
      out + O_VOCAB, ws + WS_MPART, ws + WS_LPART);
  vsm_pass2_kernel<<<dim3(cB, 4), 256, 0, stream>>>(
      out + O_VOCAB, out + O_FINAL, ws + WS_MPART, ws + WS_LPART, ws + WS_PGEN);
  scatter_kernel<<<cB, 256, 0, stream>>>(out + O_FINAL, ws + WS_PGEN,
                                         out + O_ATTN, src);
  // 6) passthrough outputs
  hipMemcpyAsync(out + O_COV, cov, (size_t)cB * cS * sizeof(float),
                 hipMemcpyDeviceToDevice, stream);
  hipMemcpyAsync(out + O_WAH, wah, (size_t)cB * cM * sizeof(float),
                 hipMemcpyDeviceToDevice, stream);
}